// Round 13
// baseline (7408.707 us; speedup 1.0000x reference)
//
#include <hip/hip_runtime.h>
#include <math.h>

#define NSWEEP_MAX 16
#define T2_TOL 2e-7f    // residual angle < 4.5e-4 -> output err ~7e-3 << 0.066
#define EPS2 1e-10f     // lambda clamp 1e-5 => lambda^2 clamp 1e-10

// One-sided Jacobi on G = S (SPD), one 64-lane wave per 64x64 matrix, lane l
// holds column l (g[64]) plus a maintained partner copy pr[64] == g[lane^m].
//
// THIS ROUND'S CHANGE (r11 was 4.32ms, VALUBusy 88%, VGPR=100 < 128 live ->
// AGPR staging inflated issued ops ~2x): the entire hot loop is VGPR-class
// inline asm ("v" constraints: AGPRs impossible, remat impossible), and every
// partner access is DPP-FUSED into its consumer (v_fmac_f32_dpp /
// v_mul_f32_dpp) so the re-pair permute costs ZERO separate instructions.
// The pairing order is a custom Hamiltonian path over all 63 XOR-masks whose
// consecutive deltas are single-op lane permutes:
//   delta 1,2   : quad_perm            delta 7 : row_half_mirror
//   delta 8     : row_ror:8            delta 16/32 : permlane16/32 self-swap
// (per-quadrant path 1,3,2,5,4,6,7,15,14,12,13,10,11,9,8 + swap-stitching;
// coverage of all 63 masks verified by construction).
// Bitwise pair-symmetry (tie-safe) kept exactly as r5-r11:
//   dot: a += dpp(pr)*g           (product exact, commutative)
//   m1 = es*prP; t = (-es)*g; g = fma(cc,g,m1); pr = fma(cc,prP,t)
//   tau from canonical (d_lo,d_hi); es/t_own sign-split by isLow.
// DPP data hazards (VALU-write -> DPP-read needs 2 wait states; the hazard
// recognizer cannot see inside asm): volatile asm (mutual program order) +
// sched_barrier(0) at every round boundary + s_nop 1 before the first
// DPP-read of each round. 4-wide grouping keeps dependent ops >=4 apart.

#define RMASK " row_mask:0xf bank_mask:0xf"
#define X1S "quad_perm:[1,0,3,2]" RMASK
#define X2S "quad_perm:[2,3,0,1]" RMASK
#define X7S "row_half_mirror" RMASK
#define X8S "row_ror:8" RMASK

__constant__ int c_delta[63] = {
    0, 2, 1, 7, 1, 2, 1, 8, 1, 2, 1, 7, 1, 2, 1,
    16, 1, 2, 1, 7, 1, 2, 1, 8, 1, 2, 1, 7, 1, 2, 1,
    32, 1, 2, 1, 7, 1, 2, 1, 8, 1, 2, 1, 7, 1, 2, 1,
    16, 1, 2, 1, 7, 1, 2, 1, 8, 1, 2, 1, 7, 1, 2, 1};

__device__ __forceinline__ float rdlane_f(float x, int l) {
    return __int_as_float(__builtin_amdgcn_readlane(__float_as_int(x), l));
}

// ---- coefficient block (shared by all round variants) -------------------
#define COEFF_BLOCK                                                        \
    const int xl = lane ^ mcur;                                            \
    const bool isLow = lane < xl;                                          \
    const float d_lo = isLow ? dO : pd;                                    \
    const float d_hi = isLow ? pd : dO;                                    \
    const float tau = (d_hi - d_lo) * __builtin_amdgcn_rcpf(2.0f * dpq);   \
    const float sqv = __builtin_amdgcn_sqrtf(fmaf(tau, tau, 1.0f));        \
    float tt = __builtin_amdgcn_rcpf(fabsf(tau) + sqv);                    \
    tt = copysignf(tt, tau);                                               \
    float cc = __builtin_amdgcn_rsqf(fmaf(tt, tt, 1.0f));                  \
    float ss = tt * cc;                                                    \
    const bool tiny = fabsf(dpq) < 1e-30f;                                 \
    cc = tiny ? 1.0f : cc;                                                 \
    ss = tiny ? 0.0f : ss;                                                 \
    tt = tiny ? 0.0f : tt;                                                 \
    const float es = isLow ? -ss : ss;                                     \
    const float nes = -es;                                                 \
    const float t_own = isLow ? tt : -tt;                                  \
    const float pdn = fmaf(t_own, dpq, pd);                                \
    dO = fmaf(-t_own, dpq, dO);                                            \
    pd = pdn;

// ---- DPP-fused round: partner = dpp(pr); pr ends holding updated partner
#define JR(CS)                                                             \
    {                                                                      \
        asm volatile("s_nop 1");                                           \
        asm volatile("v_mov_b32_dpp %0, %0 " CS : "+v"(pd));               \
        float a0 = 0.f, a1 = 0.f, a2 = 0.f, a3 = 0.f;                      \
        _Pragma("unroll") for (int s = 0; s < 64; s += 4) {                \
            asm volatile("v_fmac_f32_dpp %0, %1, %2 " CS                   \
                         : "+v"(a0) : "v"(pr[s + 0]), "v"(g[s + 0]));      \
            asm volatile("v_fmac_f32_dpp %0, %1, %2 " CS                   \
                         : "+v"(a1) : "v"(pr[s + 1]), "v"(g[s + 1]));      \
            asm volatile("v_fmac_f32_dpp %0, %1, %2 " CS                   \
                         : "+v"(a2) : "v"(pr[s + 2]), "v"(g[s + 2]));      \
            asm volatile("v_fmac_f32_dpp %0, %1, %2 " CS                   \
                         : "+v"(a3) : "v"(pr[s + 3]), "v"(g[s + 3]));      \
        }                                                                  \
        const float dpq = (a0 + a1) + (a2 + a3);                           \
        const float t2 = dpq * dpq * __builtin_amdgcn_rcpf(dO * pd);       \
        maxt2 = fmaxf(maxt2, t2);                                          \
        if (__all(t2 < T2_TOL)) {                                          \
            _Pragma("unroll") for (int s = 0; s < 64; ++s)                 \
                asm volatile("v_mov_b32_dpp %0, %0 " CS : "+v"(pr[s]));    \
        } else {                                                           \
            COEFF_BLOCK                                                    \
            _Pragma("unroll") for (int s = 0; s < 64; s += 4) {            \
                float m0, m1v, m2v, m3, t0, t1, t2v, t3;                   \
                asm volatile("v_mul_f32_dpp %0, %1, %2 " CS                \
                             : "=v"(m0) : "v"(pr[s + 0]), "v"(es));        \
                asm volatile("v_mul_f32_dpp %0, %1, %2 " CS                \
                             : "=v"(m1v) : "v"(pr[s + 1]), "v"(es));       \
                asm volatile("v_mul_f32_dpp %0, %1, %2 " CS                \
                             : "=v"(m2v) : "v"(pr[s + 2]), "v"(es));       \
                asm volatile("v_mul_f32_dpp %0, %1, %2 " CS                \
                             : "=v"(m3) : "v"(pr[s + 3]), "v"(es));        \
                asm volatile("v_mul_f32 %0, %1, %2"                        \
                             : "=v"(t0) : "v"(g[s + 0]), "v"(nes));        \
                asm volatile("v_mul_f32 %0, %1, %2"                        \
                             : "=v"(t1) : "v"(g[s + 1]), "v"(nes));        \
                asm volatile("v_mul_f32 %0, %1, %2"                        \
                             : "=v"(t2v) : "v"(g[s + 2]), "v"(nes));       \
                asm volatile("v_mul_f32 %0, %1, %2"                        \
                             : "=v"(t3) : "v"(g[s + 3]), "v"(nes));        \
                asm volatile("v_fmac_f32_dpp %0, %1, %2 " CS               \
                             : "+v"(t0) : "v"(pr[s + 0]), "v"(cc));        \
                asm volatile("v_fmac_f32_dpp %0, %1, %2 " CS               \
                             : "+v"(t1) : "v"(pr[s + 1]), "v"(cc));        \
                asm volatile("v_fmac_f32_dpp %0, %1, %2 " CS               \
                             : "+v"(t2v) : "v"(pr[s + 2]), "v"(cc));       \
                asm volatile("v_fmac_f32_dpp %0, %1, %2 " CS               \
                             : "+v"(t3) : "v"(pr[s + 3]), "v"(cc));        \
                g[s + 0] = fmaf(cc, g[s + 0], m0);                         \
                g[s + 1] = fmaf(cc, g[s + 1], m1v);                        \
                g[s + 2] = fmaf(cc, g[s + 2], m2v);                        \
                g[s + 3] = fmaf(cc, g[s + 3], m3);                         \
                pr[s + 0] = t0;                                            \
                pr[s + 1] = t1;                                            \
                pr[s + 2] = t2v;                                           \
                pr[s + 3] = t3;                                            \
            }                                                              \
        }                                                                  \
        __builtin_amdgcn_sched_barrier(0);                                 \
    }

// ---- plain round (pr already holds this round's partner; no permute) ----
#define JR_BODY_PLAIN                                                      \
    {                                                                      \
        float a0 = 0.f, a1 = 0.f, a2 = 0.f, a3 = 0.f;                      \
        _Pragma("unroll") for (int s = 0; s < 64; s += 4) {                \
            a0 = fmaf(g[s + 0], pr[s + 0], a0);                            \
            a1 = fmaf(g[s + 1], pr[s + 1], a1);                            \
            a2 = fmaf(g[s + 2], pr[s + 2], a2);                            \
            a3 = fmaf(g[s + 3], pr[s + 3], a3);                            \
        }                                                                  \
        const float dpq = (a0 + a1) + (a2 + a3);                           \
        const float t2 = dpq * dpq * __builtin_amdgcn_rcpf(dO * pd);       \
        maxt2 = fmaxf(maxt2, t2);                                          \
        if (!__all(t2 < T2_TOL)) {                                         \
            COEFF_BLOCK                                                    \
            _Pragma("unroll") for (int s = 0; s < 64; ++s) {               \
                const float m1 = es * pr[s];                               \
                const float t = nes * g[s];                                \
                g[s] = fmaf(cc, g[s], m1);                                 \
                pr[s] = fmaf(cc, pr[s], t);                                \
            }                                                              \
        }                                                                  \
        __builtin_amdgcn_sched_barrier(0);                                 \
    }

#define JR_SWAP(NBITS)                                                     \
    {                                                                      \
        asm volatile("s_nop 1");                                           \
        asm volatile("v_permlane" #NBITS "_swap_b32 %0, %0" : "+v"(pd));   \
        _Pragma("unroll") for (int s = 0; s < 64; ++s)                     \
            asm volatile("v_permlane" #NBITS "_swap_b32 %0, %0"            \
                         : "+v"(pr[s]));                                   \
        JR_BODY_PLAIN                                                      \
    }

__global__ __launch_bounds__(64, 1) void spdlog_onesided(
    const float* __restrict__ S, float* __restrict__ Out, int nmat) {
    __shared__ float X[64][64];  // 16 KB, reconstruction only
    const int lane = threadIdx.x;
    const int b = blockIdx.x;
    if (b >= nmat) return;
    const float* Sb = S + (size_t)b * 4096;
    float* Ob = Out + (size_t)b * 4096;

    // ---- load column `lane` (coalesced across lanes)
    float g[64];
    #pragma unroll 64
    for (int s = 0; s < 64; ++s) g[s] = Sb[s * 64 + lane];

    float dO = 0.0f;

    #pragma unroll 1
    for (int sweep = 0; sweep < NSWEEP_MAX; ++sweep) {
        // refresh Gram diagonal from actual column (kills drift)
        {
            float d0 = 0.f, d1 = 0.f, d2 = 0.f, d3 = 0.f;
            #pragma unroll 16
            for (int s = 0; s < 64; s += 4) {
                d0 = fmaf(g[s], g[s], d0);
                d1 = fmaf(g[s + 1], g[s + 1], d1);
                d2 = fmaf(g[s + 2], g[s + 2], d2);
                d3 = fmaf(g[s + 3], g[s + 3], d3);
            }
            dO = (d0 + d1) + (d2 + d3);
        }
        __builtin_amdgcn_sched_barrier(0);
        asm volatile("s_nop 1");
        // ---- init chain at m = 1 (pairing for round 0)
        float pd;
        asm volatile("v_mov_b32_dpp %0, %1 " X1S : "=v"(pd) : "v"(dO));
        float pr[64];
        #pragma unroll 64
        for (int s = 0; s < 64; ++s)
            asm volatile("v_mov_b32_dpp %0, %1 " X1S : "=v"(pr[s]) : "v"(g[s]));
        __builtin_amdgcn_sched_barrier(0);

        int mcur = 1;
        float maxt2 = 0.0f;
        #pragma unroll 1
        for (int t = 0; t < 63; ++t) {
            const int delta = c_delta[t];
            mcur ^= delta;
            switch (delta) {
                case 0: JR_BODY_PLAIN break;
                case 1: JR(X1S) break;
                case 2: JR(X2S) break;
                case 7: JR(X7S) break;
                case 8: JR(X8S) break;
                case 16: JR_SWAP(16) break;
                default: JR_SWAP(32) break;  // 32
            }
        }
        // ---- wave max of maxt2
        maxt2 = fmaxf(maxt2, __shfl_xor(maxt2, 1));
        maxt2 = fmaxf(maxt2, __shfl_xor(maxt2, 2));
        maxt2 = fmaxf(maxt2, __shfl_xor(maxt2, 4));
        maxt2 = fmaxf(maxt2, __shfl_xor(maxt2, 8));
        maxt2 = fmaxf(maxt2, __shfl_xor(maxt2, 16));
        maxt2 = fmaxf(maxt2, __shfl_xor(maxt2, 32));
        if (maxt2 < T2_TOL) break;  // wave-uniform
    }

    // ---- fresh column norm^2 -> eigenvalue; clamp matches ref (on lambda)
    float dfin = 0.0f;
    #pragma unroll 64
    for (int s = 0; s < 64; ++s) dfin = fmaf(g[s], g[s], dfin);
    const float w = 0.5f * logf(fmaxf(dfin, EPS2));
    const float rs = __builtin_amdgcn_rsqf(fmaxf(dfin, 1e-20f));

    // ---- reconstruction: O = U diag(w) U^T, U columns = g*rs
    #pragma unroll 64
    for (int s = 0; s < 64; ++s) X[s][lane] = g[s] * rs;  // lane-private col
    __syncthreads();
    float uw[64];
    {
        const float4* rowp = (const float4*)&X[lane][0];  // own row of U
        #pragma unroll 16
        for (int gq = 0; gq < 16; ++gq) {
            const float4 q = rowp[gq];
            uw[4 * gq + 0] = q.x;
            uw[4 * gq + 1] = q.y;
            uw[4 * gq + 2] = q.z;
            uw[4 * gq + 3] = q.w;
        }
    }
    #pragma unroll 64
    for (int c = 0; c < 64; ++c) uw[c] *= rdlane_f(w, c);
    #pragma unroll 2
    for (int i = 0; i < 64; ++i) {
        const float4* Urow = (const float4*)&X[i][0];  // wave-uniform: bcast
        float acc = 0.0f;
        #pragma unroll 16
        for (int gq = 0; gq < 16; ++gq) {
            const float4 q = Urow[gq];
            acc = fmaf(q.x, uw[4 * gq + 0], acc);
            acc = fmaf(q.y, uw[4 * gq + 1], acc);
            acc = fmaf(q.z, uw[4 * gq + 2], acc);
            acc = fmaf(q.w, uw[4 * gq + 3], acc);
        }
        Ob[i * 64 + lane] = acc;
    }
}

extern "C" void kernel_launch(void* const* d_in, const int* in_sizes, int n_in,
                              void* d_out, int out_size, void* d_ws, size_t ws_size,
                              hipStream_t stream) {
    const float* S = (const float*)d_in[0];
    float* Out = (float*)d_out;
    const int nmat = in_sizes[0] / 4096;
    spdlog_onesided<<<nmat, 64, 0, stream>>>(S, Out, nmat);
}

// Round 15
// 4241.162 us; speedup vs baseline: 1.7469x; 1.7469x over previous
//
#include <hip/hip_runtime.h>
#include <math.h>

#define NSWEEP_MAX 16
#define T2_TOL 2e-7f    // validated r12/r13: residual angle <4.5e-4, output
                        // err ~7e-3 << 0.066 threshold; absmax unchanged
#define EPS2 1e-10f     // lambda clamp 1e-5 => lambda^2 clamp 1e-10

// One-sided Jacobi on G = S (SPD), one 64-lane wave per 64x64 matrix, lane l
// holds column l in 64 VGPRs. This is the r11 structure (best measured:
// 4.32ms) with only T2_TOL relaxed — r13/r14's inline-asm residency
// experiments proved the 128-float state CAN be forced resident (VGPR 160)
// but either serialized the schedule (r13: 7.4ms) or tripped invisible
// DPP hazards (r14: NaN); reverting to the compiler-scheduled builtin form.
//
// GRAY-CODE pairing with maintained partner copy:
// rounds m_i = i^(i>>1); consecutive pairings differ by one bit delta, so
// re-pairing is a 1-2 op XOR-delta lane permute of pr[] (DPP quad_perm /
// row_half_mirror / row_ror:8 for bits 0-3; v_permlane16/32_swap self-swap
// for bits 4/5 — all HW-verified r9/r10). pr' = cc*pr - es*g_old after each
// rotation keeps the invariant pr_l == g_{l^m} bitwise (loop-carried).
//
// BITWISE pair-consistency: dpq via commuted fma (fma(a,b,c)==fma(b,a,c));
// canonical orientation tau = (d_hi-d_lo)*rcp(2dpq) identical on both
// lanes; es/t_own sign-split by isLow; pr/pd updates are exact
// negation-mirrors of the partner's own updates.
//
// Wave-uniform SKIP: if __all(t2 < T2_TOL) the round applies no rotation
// (identity — chain invariant preserved): 2 ops/elem instead of 6. With
// tol 2e-7 this fires for most late-sweep rounds.

template <int CTRL>
__device__ __forceinline__ int dpp1(int x) {
    return __builtin_amdgcn_update_dpp(0, x, CTRL, 0xF, 0xF, true);
}
template <int CTRL>
__device__ __forceinline__ float dppf1(float x) {
    return __int_as_float(dpp1<CTRL>(__float_as_int(x)));
}
__device__ __forceinline__ float swap16_self(float x) {
    asm("v_permlane16_swap_b32 %0, %0" : "+v"(x));
    return x;  // x[lane] = old x[lane^16]
}
__device__ __forceinline__ float swap32_self(float x) {
    asm("v_permlane32_swap_b32 %0, %0" : "+v"(x));
    return x;  // x[lane] = old x[lane^32]
}
__device__ __forceinline__ float rdlane_f(float x, int l) {
    return __int_as_float(__builtin_amdgcn_readlane(__float_as_int(x), l));
}

#define DPP_X1 0xB1   // quad_perm [1,0,3,2]  : lane^1
#define DPP_X2 0x4E   // quad_perm [2,3,0,1]  : lane^2
#define DPP_X3 0x1B   // quad_perm [3,2,1,0]  : lane^3
#define DPP_X7 0x141  // row_half_mirror      : lane^7
#define DPP_X8 0x128  // row_ror:8            : lane^8

__global__ __launch_bounds__(64, 2) void spdlog_onesided(
    const float* __restrict__ S, float* __restrict__ Out, int nmat) {
    __shared__ float X[64][64];  // 16 KB, reconstruction only
    const int lane = threadIdx.x;
    const int b = blockIdx.x;
    if (b >= nmat) return;
    const float* Sb = S + (size_t)b * 4096;
    float* Ob = Out + (size_t)b * 4096;

    // ---- load column `lane`: g[s] = S[s][lane] (coalesced across lanes)
    float g[64];
    #pragma unroll 64
    for (int s = 0; s < 64; ++s) g[s] = Sb[s * 64 + lane];

    float dpp = 0.0f;

    #pragma unroll 1
    for (int sweep = 0; sweep < NSWEEP_MAX; ++sweep) {
        // refresh Gram diagonal from actual column (kills drift)
        float d0 = 0.0f, d1 = 0.0f, d2 = 0.0f, d3 = 0.0f;
        #pragma unroll 16
        for (int s = 0; s < 64; s += 4) {
            d0 = fmaf(g[s], g[s], d0);
            d1 = fmaf(g[s + 1], g[s + 1], d1);
            d2 = fmaf(g[s + 2], g[s + 2], d2);
            d3 = fmaf(g[s + 3], g[s + 3], d3);
        }
        dpp = (d0 + d1) + (d2 + d3);

        // ---- initial pairing m = gray(1) = 1: fetch partner copy
        float pr[64];
        #pragma unroll 64
        for (int s = 0; s < 64; ++s) pr[s] = dppf1<DPP_X1>(g[s]);
        float pd = dppf1<DPP_X1>(dpp);

        float maxt2 = 0.0f;
        #pragma unroll 1
        for (int i = 1; i < 64; ++i) {
            if (i > 1) {
                // re-pair: next partner = current ^ delta (single bit)
                const int delta = i & (-i);
                switch (delta) {
                    case 1:
                        #pragma unroll
                        for (int s = 0; s < 64; ++s) pr[s] = dppf1<DPP_X1>(pr[s]);
                        pd = dppf1<DPP_X1>(pd);
                        break;
                    case 2:
                        #pragma unroll
                        for (int s = 0; s < 64; ++s) pr[s] = dppf1<DPP_X2>(pr[s]);
                        pd = dppf1<DPP_X2>(pd);
                        break;
                    case 4:  // XOR4 = XOR3 o XOR7
                        #pragma unroll
                        for (int s = 0; s < 64; ++s)
                            pr[s] = dppf1<DPP_X7>(dppf1<DPP_X3>(pr[s]));
                        pd = dppf1<DPP_X7>(dppf1<DPP_X3>(pd));
                        break;
                    case 8:
                        #pragma unroll
                        for (int s = 0; s < 64; ++s) pr[s] = dppf1<DPP_X8>(pr[s]);
                        pd = dppf1<DPP_X8>(pd);
                        break;
                    case 16:
                        #pragma unroll
                        for (int s = 0; s < 64; ++s) pr[s] = swap16_self(pr[s]);
                        pd = swap16_self(pd);
                        break;
                    default:  // 32
                        #pragma unroll
                        for (int s = 0; s < 64; ++s) pr[s] = swap32_self(pr[s]);
                        pd = swap32_self(pd);
                        break;
                }
            }
            const int m = i ^ (i >> 1);
            const int xl = lane ^ m;
            const bool isLow = lane < xl;
            // ---- lane-local Gram cross term (4-way split, pair-symmetric)
            float a0 = 0.0f, a1 = 0.0f, a2 = 0.0f, a3 = 0.0f;
            #pragma unroll 16
            for (int s = 0; s < 64; s += 4) {
                a0 = fmaf(g[s], pr[s], a0);
                a1 = fmaf(g[s + 1], pr[s + 1], a1);
                a2 = fmaf(g[s + 2], pr[s + 2], a2);
                a3 = fmaf(g[s + 3], pr[s + 3], a3);
            }
            const float dpq = (a0 + a1) + (a2 + a3);
            const float t2 = dpq * dpq * __builtin_amdgcn_rcpf(dpp * pd);
            maxt2 = fmaxf(maxt2, t2);
            // ---- wave-uniform skip when every pair in this round converged
            if (__all(t2 < T2_TOL)) continue;
            // ---- canonical rotation (identical bits on both lanes)
            const float d_lo = isLow ? dpp : pd;
            const float d_hi = isLow ? pd : dpp;
            const float tau = (d_hi - d_lo) * __builtin_amdgcn_rcpf(2.0f * dpq);
            const float sq = __builtin_amdgcn_sqrtf(fmaf(tau, tau, 1.0f));
            float tt = __builtin_amdgcn_rcpf(fabsf(tau) + sq);
            tt = copysignf(tt, tau);
            float cc = __builtin_amdgcn_rsqf(fmaf(tt, tt, 1.0f));
            float ss = tt * cc;
            const bool tiny = fabsf(dpq) < 1e-30f;
            cc = tiny ? 1.0f : cc;
            ss = tiny ? 0.0f : ss;
            tt = tiny ? 0.0f : tt;
            const float es = isLow ? -ss : ss;
            const float t_own = isLow ? tt : -tt;
            // diagonal updates (own exact; partner mirrors bitwise)
            const float pdn = fmaf(t_own, dpq, pd);
            dpp = fmaf(-t_own, dpq, dpp);
            pd = pdn;
            // ---- rotate own column AND maintain partner copy:
            //   g'  = cc*g  + es*pr        (own update)
            //   pr' = cc*pr - es*g_old     (== partner's own update, bitwise)
            #pragma unroll 64
            for (int s = 0; s < 64; ++s) {
                const float m1 = es * pr[s];
                const float m2 = es * g[s];
                g[s] = fmaf(cc, g[s], m1);
                pr[s] = fmaf(cc, pr[s], -m2);
            }
        }
        // ---- wave max of maxt2
        maxt2 = fmaxf(maxt2, __shfl_xor(maxt2, 1));
        maxt2 = fmaxf(maxt2, __shfl_xor(maxt2, 2));
        maxt2 = fmaxf(maxt2, __shfl_xor(maxt2, 4));
        maxt2 = fmaxf(maxt2, __shfl_xor(maxt2, 8));
        maxt2 = fmaxf(maxt2, __shfl_xor(maxt2, 16));
        maxt2 = fmaxf(maxt2, __shfl_xor(maxt2, 32));
        if (maxt2 < T2_TOL) break;  // wave-uniform
    }

    // ---- fresh column norm^2 -> eigenvalue; clamp matches ref (on lambda)
    float dfin = 0.0f;
    #pragma unroll 64
    for (int s = 0; s < 64; ++s) dfin = fmaf(g[s], g[s], dfin);
    const float w = 0.5f * logf(fmaxf(dfin, EPS2));
    const float rs = __builtin_amdgcn_rsqf(fmaxf(dfin, 1e-20f));

    // ---- reconstruction: O = U diag(w) U^T, U columns = g*rs
    #pragma unroll 64
    for (int s = 0; s < 64; ++s) X[s][lane] = g[s] * rs;  // lane-private col
    __syncthreads();
    float uw[64];
    {
        const float4* rowp = (const float4*)&X[lane][0];  // own row of U
        #pragma unroll 16
        for (int gq = 0; gq < 16; ++gq) {
            const float4 q = rowp[gq];
            uw[4 * gq + 0] = q.x;
            uw[4 * gq + 1] = q.y;
            uw[4 * gq + 2] = q.z;
            uw[4 * gq + 3] = q.w;
        }
    }
    #pragma unroll 64
    for (int c = 0; c < 64; ++c) uw[c] *= rdlane_f(w, c);
    #pragma unroll 2
    for (int i = 0; i < 64; ++i) {
        const float4* Urow = (const float4*)&X[i][0];  // wave-uniform: bcast
        float acc = 0.0f;
        #pragma unroll 16
        for (int gq = 0; gq < 16; ++gq) {
            const float4 q = Urow[gq];
            acc = fmaf(q.x, uw[4 * gq + 0], acc);
            acc = fmaf(q.y, uw[4 * gq + 1], acc);
            acc = fmaf(q.z, uw[4 * gq + 2], acc);
            acc = fmaf(q.w, uw[4 * gq + 3], acc);
        }
        Ob[i * 64 + lane] = acc;
    }
}

extern "C" void kernel_launch(void* const* d_in, const int* in_sizes, int n_in,
                              void* d_out, int out_size, void* d_ws, size_t ws_size,
                              hipStream_t stream) {
    const float* S = (const float*)d_in[0];
    float* Out = (float*)d_out;
    const int nmat = in_sizes[0] / 4096;
    spdlog_onesided<<<nmat, 64, 0, stream>>>(S, Out, nmat);
}

// Round 16
// 3615.750 us; speedup vs baseline: 2.0490x; 1.1730x over previous
//
#include <hip/hip_runtime.h>
#include <math.h>

#define NSWEEP_MAX 16
#define T2_TOL 2e-7f    // validated r12-r15: output err ~7e-3 << 0.066
#define EPS2 1e-10f     // lambda clamp 1e-5 => lambda^2 clamp 1e-10

// One-sided Jacobi on G = S (SPD), one 64-lane wave per 64x64 matrix, lane l
// holds column l. r15 structure (best: 4.24ms, VALU-issue-bound at 89%)
// with the dot / update / diag-refresh loops converted to PACKED FP32
// (<2 x float> elementwise fma -> v_pk_fma_f32, VOP3P dual-pipe): gfx950's
// 157 TF f32 peak is 2x-packed — scalar code runs at half the VALU peak.
// Packing halves the dominant loops (~415 -> ~230 wave-ops/round); the
// 32-bit lane permutes (DPP / permlane swaps) and scalar coefficient math
// are unchanged.
//
// GRAY-CODE pairing with maintained partner copy (r11): rounds
// m_i = i^(i>>1); consecutive pairings differ by one bit delta, so
// re-pairing is a 1-2 op XOR-delta lane permute of pr (DPP quad_perm /
// row_half_mirror / row_ror:8 for bits 0-3; v_permlane16/32_swap
// self-swap for bits 4/5 — HW-verified r9/r10). pr' = cc*pr - es*g_old
// after each rotation keeps pr == g_{l^m} bitwise (loop-carried).
//
// BITWISE pair-consistency: packed fma is elementwise IEEE and both pair
// lanes run identical sequences on commuted operands; horizontal reduce
// uses one fixed order; canonical tau from (d_lo,d_hi); es/t_own
// sign-split by isLow; pr/pd updates are exact negation-mirrors of the
// partner's own updates.

typedef float v2f __attribute__((ext_vector_type(2)));

__device__ __forceinline__ v2f pkfma(v2f a, v2f b, v2f c) {
    return __builtin_elementwise_fma(a, b, c);
}

template <int CTRL>
__device__ __forceinline__ int dpp1(int x) {
    return __builtin_amdgcn_update_dpp(0, x, CTRL, 0xF, 0xF, true);
}
template <int CTRL>
__device__ __forceinline__ float dppf1(float x) {
    return __int_as_float(dpp1<CTRL>(__float_as_int(x)));
}
template <int CTRL>
__device__ __forceinline__ v2f dppv2(v2f x) {
    v2f r;
    r.x = dppf1<CTRL>(x.x);
    r.y = dppf1<CTRL>(x.y);
    return r;
}
__device__ __forceinline__ float swap16_self(float x) {
    asm("v_permlane16_swap_b32 %0, %0" : "+v"(x));
    return x;  // x[lane] = old x[lane^16]
}
__device__ __forceinline__ float swap32_self(float x) {
    asm("v_permlane32_swap_b32 %0, %0" : "+v"(x));
    return x;  // x[lane] = old x[lane^32]
}
__device__ __forceinline__ v2f swap16v2(v2f x) {
    v2f r;
    r.x = swap16_self(x.x);
    r.y = swap16_self(x.y);
    return r;
}
__device__ __forceinline__ v2f swap32v2(v2f x) {
    v2f r;
    r.x = swap32_self(x.x);
    r.y = swap32_self(x.y);
    return r;
}
__device__ __forceinline__ float rdlane_f(float x, int l) {
    return __int_as_float(__builtin_amdgcn_readlane(__float_as_int(x), l));
}

#define DPP_X1 0xB1   // quad_perm [1,0,3,2]  : lane^1
#define DPP_X2 0x4E   // quad_perm [2,3,0,1]  : lane^2
#define DPP_X3 0x1B   // quad_perm [3,2,1,0]  : lane^3
#define DPP_X7 0x141  // row_half_mirror      : lane^7
#define DPP_X8 0x128  // row_ror:8            : lane^8

__global__ __launch_bounds__(64, 2) void spdlog_onesided(
    const float* __restrict__ S, float* __restrict__ Out, int nmat) {
    __shared__ float X[64][64];  // 16 KB, reconstruction only
    const int lane = threadIdx.x;
    const int b = blockIdx.x;
    if (b >= nmat) return;
    const float* Sb = S + (size_t)b * 4096;
    float* Ob = Out + (size_t)b * 4096;

    // ---- load column `lane`: rows (2k,2k+1) -> packed pair (coalesced)
    v2f g2[32];
    #pragma unroll 32
    for (int k = 0; k < 32; ++k) {
        v2f t;
        t.x = Sb[(2 * k) * 64 + lane];
        t.y = Sb[(2 * k + 1) * 64 + lane];
        g2[k] = t;
    }

    float dpp = 0.0f;

    #pragma unroll 1
    for (int sweep = 0; sweep < NSWEEP_MAX; ++sweep) {
        // refresh Gram diagonal from actual column (packed, fixed order)
        {
            v2f d0 = {0.f, 0.f}, d1 = {0.f, 0.f};
            v2f d2 = {0.f, 0.f}, d3 = {0.f, 0.f};
            #pragma unroll 8
            for (int k = 0; k < 32; k += 4) {
                d0 = pkfma(g2[k + 0], g2[k + 0], d0);
                d1 = pkfma(g2[k + 1], g2[k + 1], d1);
                d2 = pkfma(g2[k + 2], g2[k + 2], d2);
                d3 = pkfma(g2[k + 3], g2[k + 3], d3);
            }
            dpp = ((d0.x + d0.y) + (d1.x + d1.y)) +
                  ((d2.x + d2.y) + (d3.x + d3.y));
        }

        // ---- initial pairing m = gray(1) = 1: fetch partner copy
        v2f pr2[32];
        #pragma unroll 32
        for (int k = 0; k < 32; ++k) pr2[k] = dppv2<DPP_X1>(g2[k]);
        float pd = dppf1<DPP_X1>(dpp);

        float maxt2 = 0.0f;
        #pragma unroll 1
        for (int i = 1; i < 64; ++i) {
            if (i > 1) {
                // re-pair: next partner = current ^ delta (single bit)
                const int delta = i & (-i);
                switch (delta) {
                    case 1:
                        #pragma unroll
                        for (int k = 0; k < 32; ++k) pr2[k] = dppv2<DPP_X1>(pr2[k]);
                        pd = dppf1<DPP_X1>(pd);
                        break;
                    case 2:
                        #pragma unroll
                        for (int k = 0; k < 32; ++k) pr2[k] = dppv2<DPP_X2>(pr2[k]);
                        pd = dppf1<DPP_X2>(pd);
                        break;
                    case 4:  // XOR4 = XOR3 o XOR7
                        #pragma unroll
                        for (int k = 0; k < 32; ++k)
                            pr2[k] = dppv2<DPP_X7>(dppv2<DPP_X3>(pr2[k]));
                        pd = dppf1<DPP_X7>(dppf1<DPP_X3>(pd));
                        break;
                    case 8:
                        #pragma unroll
                        for (int k = 0; k < 32; ++k) pr2[k] = dppv2<DPP_X8>(pr2[k]);
                        pd = dppf1<DPP_X8>(pd);
                        break;
                    case 16:
                        #pragma unroll
                        for (int k = 0; k < 32; ++k) pr2[k] = swap16v2(pr2[k]);
                        pd = swap16_self(pd);
                        break;
                    default:  // 32
                        #pragma unroll
                        for (int k = 0; k < 32; ++k) pr2[k] = swap32v2(pr2[k]);
                        pd = swap32_self(pd);
                        break;
                }
            }
            const int m = i ^ (i >> 1);
            const int xl = lane ^ m;
            const bool isLow = lane < xl;
            // ---- packed Gram cross term (pair-symmetric: elementwise fma,
            // commuted products, same order on both pair lanes)
            v2f a0 = {0.f, 0.f}, a1 = {0.f, 0.f};
            v2f a2 = {0.f, 0.f}, a3 = {0.f, 0.f};
            #pragma unroll 8
            for (int k = 0; k < 32; k += 4) {
                a0 = pkfma(g2[k + 0], pr2[k + 0], a0);
                a1 = pkfma(g2[k + 1], pr2[k + 1], a1);
                a2 = pkfma(g2[k + 2], pr2[k + 2], a2);
                a3 = pkfma(g2[k + 3], pr2[k + 3], a3);
            }
            const float dpq = ((a0.x + a0.y) + (a1.x + a1.y)) +
                              ((a2.x + a2.y) + (a3.x + a3.y));
            const float t2 = dpq * dpq * __builtin_amdgcn_rcpf(dpp * pd);
            maxt2 = fmaxf(maxt2, t2);
            // ---- wave-uniform skip when every pair in this round converged
            if (__all(t2 < T2_TOL)) continue;
            // ---- canonical rotation (identical bits on both lanes)
            const float d_lo = isLow ? dpp : pd;
            const float d_hi = isLow ? pd : dpp;
            const float tau = (d_hi - d_lo) * __builtin_amdgcn_rcpf(2.0f * dpq);
            const float sq = __builtin_amdgcn_sqrtf(fmaf(tau, tau, 1.0f));
            float tt = __builtin_amdgcn_rcpf(fabsf(tau) + sq);
            tt = copysignf(tt, tau);
            float cc = __builtin_amdgcn_rsqf(fmaf(tt, tt, 1.0f));
            float ss = tt * cc;
            const bool tiny = fabsf(dpq) < 1e-30f;
            cc = tiny ? 1.0f : cc;
            ss = tiny ? 0.0f : ss;
            tt = tiny ? 0.0f : tt;
            const float es = isLow ? -ss : ss;
            const float t_own = isLow ? tt : -tt;
            // diagonal updates (own exact; partner mirrors bitwise)
            const float pdn = fmaf(t_own, dpq, pd);
            dpp = fmaf(-t_own, dpq, dpp);
            pd = pdn;
            // ---- packed rotate own column AND maintain partner copy:
            //   g'  = cc*g  + es*pr        (own update)
            //   pr' = cc*pr - es*g_old     (== partner's own update, bitwise)
            const v2f cc2 = {cc, cc};
            const v2f es2 = {es, es};
            const v2f nes2 = {-es, -es};
            #pragma unroll 16
            for (int k = 0; k < 32; k += 2) {
                const v2f go0 = g2[k + 0];
                const v2f go1 = g2[k + 1];
                g2[k + 0] = pkfma(cc2, go0, es2 * pr2[k + 0]);
                g2[k + 1] = pkfma(cc2, go1, es2 * pr2[k + 1]);
                pr2[k + 0] = pkfma(cc2, pr2[k + 0], nes2 * go0);
                pr2[k + 1] = pkfma(cc2, pr2[k + 1], nes2 * go1);
            }
        }
        // ---- wave max of maxt2
        maxt2 = fmaxf(maxt2, __shfl_xor(maxt2, 1));
        maxt2 = fmaxf(maxt2, __shfl_xor(maxt2, 2));
        maxt2 = fmaxf(maxt2, __shfl_xor(maxt2, 4));
        maxt2 = fmaxf(maxt2, __shfl_xor(maxt2, 8));
        maxt2 = fmaxf(maxt2, __shfl_xor(maxt2, 16));
        maxt2 = fmaxf(maxt2, __shfl_xor(maxt2, 32));
        if (maxt2 < T2_TOL) break;  // wave-uniform
    }

    // ---- fresh column norm^2 -> eigenvalue; clamp matches ref (on lambda)
    float dfin;
    {
        v2f d0 = {0.f, 0.f}, d1 = {0.f, 0.f};
        #pragma unroll 16
        for (int k = 0; k < 32; k += 2) {
            d0 = pkfma(g2[k + 0], g2[k + 0], d0);
            d1 = pkfma(g2[k + 1], g2[k + 1], d1);
        }
        dfin = (d0.x + d0.y) + (d1.x + d1.y);
    }
    const float w = 0.5f * logf(fmaxf(dfin, EPS2));
    const float rs = __builtin_amdgcn_rsqf(fmaxf(dfin, 1e-20f));

    // ---- reconstruction: O = U diag(w) U^T, U columns = g*rs
    #pragma unroll 32
    for (int k = 0; k < 32; ++k) {
        X[2 * k + 0][lane] = g2[k].x * rs;  // lane-private column
        X[2 * k + 1][lane] = g2[k].y * rs;
    }
    __syncthreads();
    float uw[64];
    {
        const float4* rowp = (const float4*)&X[lane][0];  // own row of U
        #pragma unroll 16
        for (int gq = 0; gq < 16; ++gq) {
            const float4 q = rowp[gq];
            uw[4 * gq + 0] = q.x;
            uw[4 * gq + 1] = q.y;
            uw[4 * gq + 2] = q.z;
            uw[4 * gq + 3] = q.w;
        }
    }
    #pragma unroll 64
    for (int c = 0; c < 64; ++c) uw[c] *= rdlane_f(w, c);
    #pragma unroll 2
    for (int i = 0; i < 64; ++i) {
        const float4* Urow = (const float4*)&X[i][0];  // wave-uniform: bcast
        float acc = 0.0f;
        #pragma unroll 16
        for (int gq = 0; gq < 16; ++gq) {
            const float4 q = Urow[gq];
            acc = fmaf(q.x, uw[4 * gq + 0], acc);
            acc = fmaf(q.y, uw[4 * gq + 1], acc);
            acc = fmaf(q.z, uw[4 * gq + 2], acc);
            acc = fmaf(q.w, uw[4 * gq + 3], acc);
        }
        Ob[i * 64 + lane] = acc;
    }
}

extern "C" void kernel_launch(void* const* d_in, const int* in_sizes, int n_in,
                              void* d_out, int out_size, void* d_ws, size_t ws_size,
                              hipStream_t stream) {
    const float* S = (const float*)d_in[0];
    float* Out = (float*)d_out;
    const int nmat = in_sizes[0] / 4096;
    spdlog_onesided<<<nmat, 64, 0, stream>>>(S, Out, nmat);
}